// Round 4
// baseline (119.494 us; speedup 1.0000x reference)
//
#include <hip/hip_runtime.h>
#include <hip/hip_bf16.h>

// Problem: x[16,2048,1024] f32; qk = x@Wqk^T + bqk; v = x@Wv^T + bv (D=128)
// out = softmax(qk@qk^T) @ v   -> [16,2048,128] f32
//
// Precision plan: softmax is ~argmax onto the diagonal (s_ii=|qk|^2 ~ 43 vs
// off-diag ~ 12 +- 3.8), so plain bf16 suffices; error dominated by bf16(v)
// (~0.016 absmax vs threshold 0.068). kattn processes the DIAGONAL tile
// first; all later tiles fail (mt > mrun-15) and skip softmax+PV entirely
// (neglected mass <= 64*e^-15 -> ~1e-4 output error bound).
//
// ws layout (shorts): qk_h 4M | vT 4M | Wqk_h 128K | Wv_h 128K

typedef __bf16 bf16x8 __attribute__((ext_vector_type(8)));
typedef float f32x4 __attribute__((ext_vector_type(4)));
typedef unsigned short us4 __attribute__((ext_vector_type(4)));
typedef unsigned short us8 __attribute__((ext_vector_type(8)));

static __device__ __forceinline__ unsigned short f2bf(float f) {
  unsigned u = __builtin_bit_cast(unsigned, f);
  u += 0x7fffu + ((u >> 16) & 1u);          // RNE
  return (unsigned short)(u >> 16);
}
static __device__ __forceinline__ float bf2f(unsigned short h) {
  unsigned u = ((unsigned)h) << 16;
  return __builtin_bit_cast(float, u);
}
static __device__ __forceinline__ f32x4 mfma16(bf16x8 a, bf16x8 b, f32x4 c) {
  return __builtin_amdgcn_mfma_f32_16x16x32_bf16(a, b, c, 0, 0, 0);
}
static __device__ __forceinline__ void gload16(const void* g, void* l) {
  __builtin_amdgcn_global_load_lds(
      (const __attribute__((address_space(1))) unsigned*)g,
      (__attribute__((address_space(3))) unsigned*)l, 16, 0, 0);
}

// ---------------- kernel 1: weight prep (fp32 -> bf16) ----------------
__global__ void kprep(const float* __restrict__ wqk, const float* __restrict__ wv,
                      unsigned short* __restrict__ Wqk_h, unsigned short* __restrict__ Wv_h) {
  int i = blockIdx.x * 256 + threadIdx.x;   // grid covers exactly 128*1024
  Wqk_h[i] = f2bf(wqk[i]);
  Wv_h[i] = f2bf(wv[i]);
}

// ---------------- kernel 2: projections (bf16, dbuf, counted vmcnt) ---------
// block = 64 rows, 4 waves column-partitioned. LDS buffer (20 KB):
// Xh [64][32] @0 | Wh [32 slots.. 2 per wave][32] @4096 | Wv @12288
#define XH_OFF 0
#define WH_OFF 4096
#define WV_OFF 12288
#define PBUF_B 20480

__launch_bounds__(256, 4)
__global__ void kproj(const float* __restrict__ x,
                      const unsigned short* __restrict__ Wqk_h,
                      const unsigned short* __restrict__ Wv_h,
                      const float* __restrict__ bqk, const float* __restrict__ bv,
                      unsigned short* __restrict__ qk_h,
                      unsigned short* __restrict__ vT) {
  extern __shared__ char smem[];            // 2 * PBUF_B = 40 KB (dynamic)
  const int t = threadIdx.x;
  const int lane = t & 63;
  const int w = t >> 6;
  const int r_lo = lane & 15;
  const int g = lane >> 4;
  const long mb = (long)blockIdx.x * 64;

  const int xrow = t >> 2;                  // X staging: row, 8-k chunk
  const int xkc = t & 3;
  const int wgrow = (lane >> 2);            // W staging: row in 16-row slot
  const int wgcol = (lane & 3) * 8;         // k offset (shorts)

  f32x4 zero = {0.f, 0.f, 0.f, 0.f};
  f32x4 acc[4][4];                          // [rowblock][qk0,qk1,v0,v1]
#pragma unroll
  for (int i = 0; i < 4; ++i)
#pragma unroll
    for (int j = 0; j < 4; ++j) acc[i][j] = zero;

  // ---- prologue: X(0) regs, W(0) gloads -> buf0, convert+write X(0) ----
  {
    const float* px = x + (mb + xrow) * 1024 + xkc * 8;
    float4 xa = *(const float4*)px;
    float4 xb = *(const float4*)(px + 4);
#pragma unroll
    for (int i = 0; i < 2; ++i) {
      int s = 2 * w + i;
      long goff = (long)(s * 16 + wgrow) * 1024 + wgcol;
      gload16(Wqk_h + goff, smem + WH_OFF + s * 1024);
      gload16(Wv_h + goff, smem + WV_OFF + s * 1024);
    }
    us8 hv;
#pragma unroll
    for (int i = 0; i < 4; ++i) {
      float fa = (i == 0) ? xa.x : (i == 1) ? xa.y : (i == 2) ? xa.z : xa.w;
      float fb = (i == 0) ? xb.x : (i == 1) ? xb.y : (i == 2) ? xb.z : xb.w;
      hv[i] = f2bf(fa);
      hv[4 + i] = f2bf(fb);
    }
    *(us8*)(smem + XH_OFF + xrow * 64 + xkc * 16) = hv;
  }

  // ---- main loop ----
  for (int ks = 0; ks < 32; ++ks) {
    char* cur = smem + (ks & 1) * PBUF_B;
    char* nxt = smem + ((ks & 1) ^ 1) * PBUF_B;

    float4 xa, xb;
    if (ks < 31) {
      const float* px = x + (mb + xrow) * 1024 + (ks + 1) * 32 + xkc * 8;
      xa = *(const float4*)px;              // X first: its use waits vmcnt(4)
      xb = *(const float4*)(px + 4);
#pragma unroll
      for (int i = 0; i < 2; ++i) {
        int s = 2 * w + i;
        long goff = (long)(s * 16 + wgrow) * 1024 + (ks + 1) * 32 + wgcol;
        gload16(Wqk_h + goff, nxt + WH_OFF + s * 1024);
        gload16(Wv_h + goff, nxt + WV_OFF + s * 1024);
      }
      asm volatile("s_waitcnt vmcnt(6) lgkmcnt(0)" ::: "memory");
    } else {
      asm volatile("s_waitcnt vmcnt(0) lgkmcnt(0)" ::: "memory");
    }
    __builtin_amdgcn_s_barrier();

    const unsigned short* Xh = (const unsigned short*)(cur + XH_OFF);
    const unsigned short* Wh = (const unsigned short*)(cur + WH_OFF);
    const unsigned short* Wv = (const unsigned short*)(cur + WV_OFF);

    bf16x8 Bh0 = *(const bf16x8*)(Wh + ((2 * w) * 16 + r_lo) * 32 + g * 8);
    bf16x8 Bh1 = *(const bf16x8*)(Wh + ((2 * w + 1) * 16 + r_lo) * 32 + g * 8);
    bf16x8 Bv0 = *(const bf16x8*)(Wv + (w * 32 + r_lo) * 32 + g * 8);
    bf16x8 Bv1 = *(const bf16x8*)(Wv + (w * 32 + 16 + r_lo) * 32 + g * 8);

    __builtin_amdgcn_s_setprio(1);
#pragma unroll
    for (int rb = 0; rb < 4; ++rb) {
      bf16x8 Ah = *(const bf16x8*)(Xh + (rb * 16 + r_lo) * 32 + g * 8);
      acc[rb][0] = mfma16(Ah, Bh0, acc[rb][0]);
      acc[rb][1] = mfma16(Ah, Bh1, acc[rb][1]);
      acc[rb][2] = mfma16(Ah, Bv0, acc[rb][2]);
      acc[rb][3] = mfma16(Ah, Bv1, acc[rb][3]);
    }
    __builtin_amdgcn_s_setprio(0);

    if (ks < 31) {
      us8 hv;
#pragma unroll
      for (int i = 0; i < 4; ++i) {
        float fa = (i == 0) ? xa.x : (i == 1) ? xa.y : (i == 2) ? xa.z : xa.w;
        float fb = (i == 0) ? xb.x : (i == 1) ? xb.y : (i == 2) ? xb.z : xb.w;
        hv[i] = f2bf(fa);
        hv[4 + i] = f2bf(fb);
      }
      *(us8*)(nxt + XH_OFF + xrow * 64 + xkc * 16) = hv;
    }
    __builtin_amdgcn_s_barrier();
  }

  // ---- epilogue: qk store (D layout: row=g*4+r, col=r_lo) ----
  {
    float bq0 = bqk[(2 * w) * 16 + r_lo];
    float bq1 = bqk[(2 * w + 1) * 16 + r_lo];
#pragma unroll
    for (int rb = 0; rb < 4; ++rb) {
#pragma unroll
      for (int r = 0; r < 4; ++r) {
        long m = mb + rb * 16 + g * 4 + r;
        int o0 = (2 * w) * 16 + r_lo;
        qk_h[m * 128 + o0] = f2bf(acc[rb][0][r] + bq0);
        qk_h[m * 128 + o0 + 16] = f2bf(acc[rb][1][r] + bq1);
      }
    }
  }

  // ---- epilogue: v -> LDS transpose -> vT[b][d][n] coalesced ----
  __syncthreads();
  {
    unsigned short* T = (unsigned short*)smem;       // [128][68]
    float bv0 = bv[w * 32 + r_lo];
    float bv1 = bv[w * 32 + 16 + r_lo];
#pragma unroll
    for (int rb = 0; rb < 4; ++rb) {
#pragma unroll
      for (int r = 0; r < 4; ++r) {
        int n = rb * 16 + g * 4 + r;
        T[(w * 32 + r_lo) * 68 + n] = f2bf(acc[rb][2][r] + bv0);
        T[(w * 32 + 16 + r_lo) * 68 + n] = f2bf(acc[rb][3][r] + bv1);
      }
    }
    __syncthreads();
    const long bb = mb >> 11;        // batch
    const long n0 = mb & 2047;       // n within batch
#pragma unroll
    for (int it = 0; it < 8; ++it) {
      int d = (t >> 4) + 16 * it;
      int m0 = (t & 15) * 4;
      us4 vv = *(const us4*)(T + d * 68 + m0);
      *(us4*)(vT + (bb * 128 + d) * 2048 + n0 + m0) = vv;
    }
  }
}

// ---------------- kernel 3: flash attention (diagonal-first order) ----------
// block = 64 q rows of one batch, 4 waves x 16 q rows; KV tiles of 64,
// processed in order jt = qt, qt+1, ..., 31, 0, ..., qt-1 so the running max
// locks to the diagonal on tile 0 and later tiles skip softmax+PV.
// LDS: K dbuf 2x16K @0 | V dbuf 2x16K @32768 | P 4x2304 @65536 -> 74752 B
#define AK_OFF 0
#define AV_OFF 32768
#define AP_OFF 65536
#define ASMEM_B 74752

__launch_bounds__(256, 2)
__global__ void kattn(const unsigned short* __restrict__ qk_h,
                      const unsigned short* __restrict__ vT,
                      float* __restrict__ out) {
  __shared__ char smem[ASMEM_B];
  const int t = threadIdx.x;
  const int lane = t & 63;
  const int w = t >> 6;
  const int r_lo = lane & 15;
  const int g = lane >> 4;
  const long b = blockIdx.x >> 5;
  const int qt = blockIdx.x & 31;
  const long qrow = b * 2048 + qt * 64 + w * 16 + r_lo;

  // Q fragments; pin materialization BEFORE the loop so the compiler's
  // vmcnt wait for them doesn't land inside the pipelined loop.
  f32x4 Qm[4];
#pragma unroll
  for (int kk = 0; kk < 4; ++kk)
    Qm[kk] = *(const f32x4*)(qk_h + qrow * 128 + kk * 32 + g * 8);
#pragma unroll
  for (int kk = 0; kk < 4; ++kk)
    asm volatile("" : "+v"(Qm[kk]));

  f32x4 zero = {0.f, 0.f, 0.f, 0.f};
  f32x4 Oa[8];
#pragma unroll
  for (int i = 0; i < 8; ++i) Oa[i] = zero;
  float mrun = -1e30f, lrun = 0.f;

  unsigned short* P = (unsigned short*)(smem + AP_OFF + w * 2304);  // [16][72]

  // ---- prologue: stage tile jt=qt into buf0 (8 gload16 per thread) ----
  {
    const long jb = b * 2048 + (long)qt * 64;
    const int jn = qt * 64;
#pragma unroll
    for (int c = 0; c < 4; ++c) {
      int slot = w * 4 + c;
      int row = slot * 4 + (lane >> 4);
      int chunk = (lane & 15) ^ (row & 7);
      gload16((const char*)(qk_h + (jb + row) * 128) + chunk * 16,
              smem + AK_OFF + slot * 1024);
      int rowd = slot * 8 + (lane >> 3);
      int chv = (lane & 7) ^ (rowd & 7);
      gload16((const char*)(vT + (b * 128 + rowd) * 2048 + jn) + chv * 16,
              smem + AV_OFF + slot * 1024);
    }
  }

  for (int ti = 0; ti < 32; ++ti) {
    const int cb = ti & 1;
    if (ti < 31) {
      // stage tile (qt+ti+1)%32 into the other buffer (8 gload16)
      int jt2 = qt + ti + 1;
      if (jt2 >= 32) jt2 -= 32;
      const long jb = b * 2048 + (long)jt2 * 64;
      const int jn = jt2 * 64;
      char* Kd = smem + AK_OFF + (cb ^ 1) * 16384;
      char* Vd = smem + AV_OFF + (cb ^ 1) * 16384;
#pragma unroll
      for (int c = 0; c < 4; ++c) {
        int slot = w * 4 + c;
        int row = slot * 4 + (lane >> 4);
        int chunk = (lane & 15) ^ (row & 7);
        gload16((const char*)(qk_h + (jb + row) * 128) + chunk * 16,
                Kd + slot * 1024);
        int rowd = slot * 8 + (lane >> 3);
        int chv = (lane & 7) ^ (rowd & 7);
        gload16((const char*)(vT + (b * 128 + rowd) * 2048 + jn) + chv * 16,
                Vd + slot * 1024);
      }
      asm volatile("s_waitcnt vmcnt(8)" ::: "memory");   // current tile landed
    } else {
      asm volatile("s_waitcnt vmcnt(0)" ::: "memory");
    }
    __builtin_amdgcn_s_barrier();

    const char* Kb = smem + AK_OFF + cb * 16384;
    const char* Vb = smem + AV_OFF + cb * 16384;

    // ---- S^T[j][q] = K . Q^T ----
    f32x4 sAcc[4];
#pragma unroll
    for (int jc = 0; jc < 4; ++jc) sAcc[jc] = zero;
    __builtin_amdgcn_s_setprio(1);
#pragma unroll
    for (int jc = 0; jc < 4; ++jc) {
      int krow = jc * 16 + r_lo;
#pragma unroll
      for (int kk = 0; kk < 4; ++kk) {
        int chunk = (kk * 4 + g) ^ (krow & 7);
        bf16x8 Kh = *(const bf16x8*)(Kb + krow * 256 + chunk * 16);
        sAcc[jc] = mfma16(Kh, __builtin_bit_cast(bf16x8, Qm[kk]), sAcc[jc]);
      }
    }
    __builtin_amdgcn_s_setprio(0);

    // ---- online softmax (defer-max THR=8; tile-skip at -15) ----
    float mt = -1e30f;
#pragma unroll
    for (int jc = 0; jc < 4; ++jc)
#pragma unroll
      for (int r = 0; r < 4; ++r) mt = fmaxf(mt, sAcc[jc][r]);
    mt = fmaxf(mt, __shfl_xor(mt, 16));
    mt = fmaxf(mt, __shfl_xor(mt, 32));

    if (__any(mt > mrun - 15.f)) {         // tile contributes (bound: 64*e^-15)
      if (__any(mt > mrun + 8.f)) {        // T13: rescale only on real growth
        float mnew = fmaxf(mrun, mt);
        float alpha = __expf(mrun - mnew);
        lrun *= alpha;
#pragma unroll
        for (int r = 0; r < 4; ++r) {
          float ar = __shfl(alpha, g * 4 + r);
#pragma unroll
          for (int dc = 0; dc < 8; ++dc) Oa[dc][r] *= ar;
        }
        mrun = mnew;
      }
      float ls = 0.f;
#pragma unroll
      for (int jc = 0; jc < 4; ++jc) {
        us4 pk;
#pragma unroll
        for (int r = 0; r < 4; ++r) {
          float p = __expf(sAcc[jc][r] - mrun);   // bounded by e^8
          pk[r] = f2bf(p);
          ls += bf2f(pk[r]);                       // denom consistent w/ numer
        }
        *(us4*)(P + r_lo * 72 + jc * 16 + g * 4) = pk;
      }
      ls += __shfl_xor(ls, 16);
      ls += __shfl_xor(ls, 32);
      lrun += ls;

      // ---- PV: O[q][d] += P[q][j] * V[j][d] ----
      __builtin_amdgcn_s_setprio(1);
#pragma unroll
      for (int ks = 0; ks < 2; ++ks) {
        bf16x8 Pa = *(const bf16x8*)(P + r_lo * 72 + ks * 32 + g * 8);
#pragma unroll
        for (int dc = 0; dc < 8; ++dc) {
          int d = dc * 16 + r_lo;
          int chunk = (ks * 4 + g) ^ (d & 7);
          bf16x8 Vb8 = *(const bf16x8*)(Vb + d * 128 + chunk * 16);
          Oa[dc] = mfma16(Pa, Vb8, Oa[dc]);
        }
      }
      __builtin_amdgcn_s_setprio(0);
    }
    __builtin_amdgcn_s_barrier();
  }

  // ---- epilogue: normalize and store fp32 ----
#pragma unroll
  for (int r = 0; r < 4; ++r) {
    float li = 1.f / __shfl(lrun, g * 4 + r);
    long orow = b * 2048 + qt * 64 + w * 16 + g * 4 + r;
#pragma unroll
    for (int dc = 0; dc < 8; ++dc) {
      out[orow * 128 + dc * 16 + r_lo] = Oa[dc][r] * li;
    }
  }
}

extern "C" void kernel_launch(void* const* d_in, const int* in_sizes, int n_in,
                              void* d_out, int out_size, void* d_ws, size_t ws_size,
                              hipStream_t stream) {
  const float* x     = (const float*)d_in[0];
  const float* wqk_w = (const float*)d_in[1];
  const float* wqk_b = (const float*)d_in[2];
  const float* wv_w  = (const float*)d_in[3];
  const float* wv_b  = (const float*)d_in[4];
  float* out = (float*)d_out;

  unsigned short* qk_h  = (unsigned short*)d_ws;             // 32768*128
  unsigned short* vT    = qk_h + 32768 * 128;                // [16][128][2048]
  unsigned short* Wqk_h = vT + 16 * 128 * 2048;              // [128][1024]
  unsigned short* Wv_h  = Wqk_h + 128 * 1024;

  hipLaunchKernelGGL(kprep, dim3(512), dim3(256), 0, stream,
                     wqk_w, wv_w, Wqk_h, Wv_h);
  hipLaunchKernelGGL(kproj, dim3(512), dim3(256), 2 * PBUF_B, stream,
                     x, Wqk_h, Wv_h, wqk_b, wv_b, qk_h, vT);
  hipLaunchKernelGGL(kattn, dim3(512), dim3(256), 0, stream,
                     qk_h, vT, out);
}

// Round 5
// 79.868 us; speedup vs baseline: 1.4961x; 1.4961x over previous
//
#include <hip/hip_runtime.h>
#include <hip/hip_bf16.h>

// Problem: x[16,2048,1024] f32; qk = x@Wqk^T + bqk; v = x@Wv^T + bv (D=128)
// out = softmax(qk@qk^T) @ v   -> [16,2048,128] f32
//
// Precision plan: softmax is ~argmax onto the diagonal (s_ii=|qk|^2 ~ 43 vs
// off-diag ~ 12 +- 3.8), so plain bf16 suffices; error dominated by bf16(v)
// (~0.016 absmax vs threshold 0.068). kattn processes the DIAGONAL tile
// first (locks the running max), then sweeps tiles 0..31 in CANONICAL order
// (same across all blocks of a batch -> cross-block L2 reuse); non-diagonal
// tiles fail (mt > mrun-15) and skip softmax+PV (mass <= 64*e^-15 ~ 1e-4).
// V is NOT staged: PV (rare path) reads V fragments direct from L2.
//
// ws layout (shorts): qk_h 4M | vT 4M | Wqk_h 128K | Wv_h 128K

typedef __bf16 bf16x8 __attribute__((ext_vector_type(8)));
typedef float f32x4 __attribute__((ext_vector_type(4)));
typedef unsigned short us4 __attribute__((ext_vector_type(4)));
typedef unsigned short us8 __attribute__((ext_vector_type(8)));

static __device__ __forceinline__ unsigned short f2bf(float f) {
  unsigned u = __builtin_bit_cast(unsigned, f);
  u += 0x7fffu + ((u >> 16) & 1u);          // RNE
  return (unsigned short)(u >> 16);
}
static __device__ __forceinline__ float bf2f(unsigned short h) {
  unsigned u = ((unsigned)h) << 16;
  return __builtin_bit_cast(float, u);
}
static __device__ __forceinline__ f32x4 mfma16(bf16x8 a, bf16x8 b, f32x4 c) {
  return __builtin_amdgcn_mfma_f32_16x16x32_bf16(a, b, c, 0, 0, 0);
}
static __device__ __forceinline__ void gload16(const void* g, void* l) {
  __builtin_amdgcn_global_load_lds(
      (const __attribute__((address_space(1))) unsigned*)g,
      (__attribute__((address_space(3))) unsigned*)l, 16, 0, 0);
}

// ---------------- kernel 1: weight prep (fp32 -> bf16) ----------------
__global__ void kprep(const float* __restrict__ wqk, const float* __restrict__ wv,
                      unsigned short* __restrict__ Wqk_h, unsigned short* __restrict__ Wv_h) {
  int i = blockIdx.x * 256 + threadIdx.x;   // grid covers exactly 128*1024
  Wqk_h[i] = f2bf(wqk[i]);
  Wv_h[i] = f2bf(wv[i]);
}

// ---------------- kernel 2: projections (bf16, dbuf, counted vmcnt) ---------
// block = 64 rows, 4 waves column-partitioned. LDS buffer (20 KB):
// Xh [64][32] @0 | Wh [32 slots.. 2 per wave][32] @4096 | Wv @12288
#define XH_OFF 0
#define WH_OFF 4096
#define WV_OFF 12288
#define PBUF_B 20480

__launch_bounds__(256, 4)
__global__ void kproj(const float* __restrict__ x,
                      const unsigned short* __restrict__ Wqk_h,
                      const unsigned short* __restrict__ Wv_h,
                      const float* __restrict__ bqk, const float* __restrict__ bv,
                      unsigned short* __restrict__ qk_h,
                      unsigned short* __restrict__ vT) {
  extern __shared__ char smem[];            // 2 * PBUF_B = 40 KB (dynamic)
  const int t = threadIdx.x;
  const int lane = t & 63;
  const int w = t >> 6;
  const int r_lo = lane & 15;
  const int g = lane >> 4;
  const long mb = (long)blockIdx.x * 64;

  const int xrow = t >> 2;                  // X staging: row, 8-k chunk
  const int xkc = t & 3;
  const int wgrow = (lane >> 2);            // W staging: row in 16-row slot
  const int wgcol = (lane & 3) * 8;         // k offset (shorts)

  f32x4 zero = {0.f, 0.f, 0.f, 0.f};
  f32x4 acc[4][4];                          // [rowblock][qk0,qk1,v0,v1]
#pragma unroll
  for (int i = 0; i < 4; ++i)
#pragma unroll
    for (int j = 0; j < 4; ++j) acc[i][j] = zero;

  // ---- prologue: X(0) regs, W(0) gloads -> buf0, convert+write X(0) ----
  {
    const float* px = x + (mb + xrow) * 1024 + xkc * 8;
    float4 xa = *(const float4*)px;
    float4 xb = *(const float4*)(px + 4);
#pragma unroll
    for (int i = 0; i < 2; ++i) {
      int s = 2 * w + i;
      long goff = (long)(s * 16 + wgrow) * 1024 + wgcol;
      gload16(Wqk_h + goff, smem + WH_OFF + s * 1024);
      gload16(Wv_h + goff, smem + WV_OFF + s * 1024);
    }
    us8 hv;
#pragma unroll
    for (int i = 0; i < 4; ++i) {
      float fa = (i == 0) ? xa.x : (i == 1) ? xa.y : (i == 2) ? xa.z : xa.w;
      float fb = (i == 0) ? xb.x : (i == 1) ? xb.y : (i == 2) ? xb.z : xb.w;
      hv[i] = f2bf(fa);
      hv[4 + i] = f2bf(fb);
    }
    *(us8*)(smem + XH_OFF + xrow * 64 + xkc * 16) = hv;
  }

  // ---- main loop ----
  for (int ks = 0; ks < 32; ++ks) {
    char* cur = smem + (ks & 1) * PBUF_B;
    char* nxt = smem + ((ks & 1) ^ 1) * PBUF_B;

    float4 xa, xb;
    if (ks < 31) {
      const float* px = x + (mb + xrow) * 1024 + (ks + 1) * 32 + xkc * 8;
      xa = *(const float4*)px;              // X first: its use waits vmcnt(4)
      xb = *(const float4*)(px + 4);
#pragma unroll
      for (int i = 0; i < 2; ++i) {
        int s = 2 * w + i;
        long goff = (long)(s * 16 + wgrow) * 1024 + (ks + 1) * 32 + wgcol;
        gload16(Wqk_h + goff, nxt + WH_OFF + s * 1024);
        gload16(Wv_h + goff, nxt + WV_OFF + s * 1024);
      }
      asm volatile("s_waitcnt vmcnt(6) lgkmcnt(0)" ::: "memory");
    } else {
      asm volatile("s_waitcnt vmcnt(0) lgkmcnt(0)" ::: "memory");
    }
    __builtin_amdgcn_s_barrier();

    const unsigned short* Xh = (const unsigned short*)(cur + XH_OFF);
    const unsigned short* Wh = (const unsigned short*)(cur + WH_OFF);
    const unsigned short* Wv = (const unsigned short*)(cur + WV_OFF);

    bf16x8 Bh0 = *(const bf16x8*)(Wh + ((2 * w) * 16 + r_lo) * 32 + g * 8);
    bf16x8 Bh1 = *(const bf16x8*)(Wh + ((2 * w + 1) * 16 + r_lo) * 32 + g * 8);
    bf16x8 Bv0 = *(const bf16x8*)(Wv + (w * 32 + r_lo) * 32 + g * 8);
    bf16x8 Bv1 = *(const bf16x8*)(Wv + (w * 32 + 16 + r_lo) * 32 + g * 8);

    __builtin_amdgcn_s_setprio(1);
#pragma unroll
    for (int rb = 0; rb < 4; ++rb) {
      bf16x8 Ah = *(const bf16x8*)(Xh + (rb * 16 + r_lo) * 32 + g * 8);
      acc[rb][0] = mfma16(Ah, Bh0, acc[rb][0]);
      acc[rb][1] = mfma16(Ah, Bh1, acc[rb][1]);
      acc[rb][2] = mfma16(Ah, Bv0, acc[rb][2]);
      acc[rb][3] = mfma16(Ah, Bv1, acc[rb][3]);
    }
    __builtin_amdgcn_s_setprio(0);

    if (ks < 31) {
      us8 hv;
#pragma unroll
      for (int i = 0; i < 4; ++i) {
        float fa = (i == 0) ? xa.x : (i == 1) ? xa.y : (i == 2) ? xa.z : xa.w;
        float fb = (i == 0) ? xb.x : (i == 1) ? xb.y : (i == 2) ? xb.z : xb.w;
        hv[i] = f2bf(fa);
        hv[4 + i] = f2bf(fb);
      }
      *(us8*)(nxt + XH_OFF + xrow * 64 + xkc * 16) = hv;
    }
    __builtin_amdgcn_s_barrier();
  }

  // ---- epilogue: qk store (D layout: row=g*4+r, col=r_lo) ----
  {
    float bq0 = bqk[(2 * w) * 16 + r_lo];
    float bq1 = bqk[(2 * w + 1) * 16 + r_lo];
#pragma unroll
    for (int rb = 0; rb < 4; ++rb) {
#pragma unroll
      for (int r = 0; r < 4; ++r) {
        long m = mb + rb * 16 + g * 4 + r;
        int o0 = (2 * w) * 16 + r_lo;
        qk_h[m * 128 + o0] = f2bf(acc[rb][0][r] + bq0);
        qk_h[m * 128 + o0 + 16] = f2bf(acc[rb][1][r] + bq1);
      }
    }
  }

  // ---- epilogue: v -> LDS transpose -> vT[b][d][n] coalesced ----
  __syncthreads();
  {
    unsigned short* T = (unsigned short*)smem;       // [128][68]
    float bv0 = bv[w * 32 + r_lo];
    float bv1 = bv[w * 32 + 16 + r_lo];
#pragma unroll
    for (int rb = 0; rb < 4; ++rb) {
#pragma unroll
      for (int r = 0; r < 4; ++r) {
        int n = rb * 16 + g * 4 + r;
        T[(w * 32 + r_lo) * 68 + n] = f2bf(acc[rb][2][r] + bv0);
        T[(w * 32 + 16 + r_lo) * 68 + n] = f2bf(acc[rb][3][r] + bv1);
      }
    }
    __syncthreads();
    const long bb = mb >> 11;        // batch
    const long n0 = mb & 2047;       // n within batch
#pragma unroll
    for (int it = 0; it < 8; ++it) {
      int d = (t >> 4) + 16 * it;
      int m0 = (t & 15) * 4;
      us4 vv = *(const us4*)(T + d * 68 + m0);
      *(us4*)(vT + (bb * 128 + d) * 2048 + n0 + m0) = vv;
    }
  }
}

// ---------------- kernel 3: flash attention (diag-first, canonical sweep) ---
// block = 64 q rows of one batch, 4 waves x 16 q rows; KV tiles of 64.
// Tile order: ti=0 -> qt (diagonal); ti>=1 -> jt=(ti-1)+((ti-1)>=qt), i.e.
// canonical 0..31 minus qt -> all blocks sweep K in the same order (L2 reuse).
// K only is staged (dbuf); V is read direct from global in the rare PV path.
// LDS: K dbuf 2x16K @0 | P 4x2304 @32768 -> 41984 B
#define AK_OFF 0
#define AP_OFF 32768
#define ASMEM_B 41984

__launch_bounds__(256, 3)
__global__ void kattn(const unsigned short* __restrict__ qk_h,
                      const unsigned short* __restrict__ vT,
                      float* __restrict__ out) {
  __shared__ char smem[ASMEM_B];
  const int t = threadIdx.x;
  const int lane = t & 63;
  const int w = t >> 6;
  const int r_lo = lane & 15;
  const int g = lane >> 4;
  const long b = blockIdx.x >> 5;
  const int qt = blockIdx.x & 31;
  const long qrow = b * 2048 + qt * 64 + w * 16 + r_lo;

  // Q fragments; pin materialization BEFORE the loop so the compiler's
  // vmcnt wait for them doesn't land inside the pipelined loop.
  f32x4 Qm[4];
#pragma unroll
  for (int kk = 0; kk < 4; ++kk)
    Qm[kk] = *(const f32x4*)(qk_h + qrow * 128 + kk * 32 + g * 8);
#pragma unroll
  for (int kk = 0; kk < 4; ++kk)
    asm volatile("" : "+v"(Qm[kk]));

  f32x4 zero = {0.f, 0.f, 0.f, 0.f};
  f32x4 Oa[8];
#pragma unroll
  for (int i = 0; i < 8; ++i) Oa[i] = zero;
  float mrun = -1e30f, lrun = 0.f;

  unsigned short* P = (unsigned short*)(smem + AP_OFF + w * 2304);  // [16][72]

  // ---- prologue: stage K of tile jt=qt into buf0 (4 gload16 per thread) ----
  {
    const long jb = b * 2048 + (long)qt * 64;
#pragma unroll
    for (int c = 0; c < 4; ++c) {
      int slot = w * 4 + c;
      int row = slot * 4 + (lane >> 4);
      int chunk = (lane & 15) ^ (row & 7);
      gload16((const char*)(qk_h + (jb + row) * 128) + chunk * 16,
              smem + AK_OFF + slot * 1024);
    }
  }

  for (int ti = 0; ti < 32; ++ti) {
    const int cb = ti & 1;
    // current tile index (diag first, then canonical skipping qt)
    const int jcur = (ti == 0) ? qt : (ti - 1) + ((ti - 1) >= qt ? 1 : 0);
    if (ti < 31) {
      // next tile jt = ti + (ti >= qt)
      const int jnx = ti + (ti >= qt ? 1 : 0);
      const long jb = b * 2048 + (long)jnx * 64;
      char* Kd = smem + AK_OFF + (cb ^ 1) * 16384;
#pragma unroll
      for (int c = 0; c < 4; ++c) {
        int slot = w * 4 + c;
        int row = slot * 4 + (lane >> 4);
        int chunk = (lane & 15) ^ (row & 7);
        gload16((const char*)(qk_h + (jb + row) * 128) + chunk * 16,
                Kd + slot * 1024);
      }
      asm volatile("s_waitcnt vmcnt(4)" ::: "memory");   // current tile landed
    } else {
      asm volatile("s_waitcnt vmcnt(0)" ::: "memory");
    }
    __builtin_amdgcn_s_barrier();

    const char* Kb = smem + AK_OFF + cb * 16384;

    // ---- S^T[j][q] = K . Q^T ----
    f32x4 sAcc[4];
#pragma unroll
    for (int jc = 0; jc < 4; ++jc) sAcc[jc] = zero;
    __builtin_amdgcn_s_setprio(1);
#pragma unroll
    for (int jc = 0; jc < 4; ++jc) {
      int krow = jc * 16 + r_lo;
#pragma unroll
      for (int kk = 0; kk < 4; ++kk) {
        int chunk = (kk * 4 + g) ^ (krow & 7);
        bf16x8 Kh = *(const bf16x8*)(Kb + krow * 256 + chunk * 16);
        sAcc[jc] = mfma16(Kh, __builtin_bit_cast(bf16x8, Qm[kk]), sAcc[jc]);
      }
    }
    __builtin_amdgcn_s_setprio(0);

    // ---- online softmax (defer-max THR=8; tile-skip at -15) ----
    float mt = -1e30f;
#pragma unroll
    for (int jc = 0; jc < 4; ++jc)
#pragma unroll
      for (int r = 0; r < 4; ++r) mt = fmaxf(mt, sAcc[jc][r]);
    mt = fmaxf(mt, __shfl_xor(mt, 16));
    mt = fmaxf(mt, __shfl_xor(mt, 32));

    if (__any(mt > mrun - 15.f)) {         // tile contributes (bound: 64*e^-15)
      if (__any(mt > mrun + 8.f)) {        // T13: rescale only on real growth
        float mnew = fmaxf(mrun, mt);
        float alpha = __expf(mrun - mnew);
        lrun *= alpha;
#pragma unroll
        for (int r = 0; r < 4; ++r) {
          float ar = __shfl(alpha, g * 4 + r);
#pragma unroll
          for (int dc = 0; dc < 8; ++dc) Oa[dc][r] *= ar;
        }
        mrun = mnew;
      }
      float ls = 0.f;
#pragma unroll
      for (int jc = 0; jc < 4; ++jc) {
        us4 pk;
#pragma unroll
        for (int r = 0; r < 4; ++r) {
          float p = __expf(sAcc[jc][r] - mrun);   // bounded by e^8
          pk[r] = f2bf(p);
          ls += bf2f(pk[r]);                       // denom consistent w/ numer
        }
        *(us4*)(P + r_lo * 72 + jc * 16 + g * 4) = pk;
      }
      ls += __shfl_xor(ls, 16);
      ls += __shfl_xor(ls, 32);
      lrun += ls;

      // ---- PV: O[q][d] += P[q][j] * V[j][d]; V direct from global (L2) ----
      const unsigned short* Vg = vT + (long)b * 128 * 2048 + jcur * 64;
      __builtin_amdgcn_s_setprio(1);
#pragma unroll
      for (int ks = 0; ks < 2; ++ks) {
        bf16x8 Pa = *(const bf16x8*)(P + r_lo * 72 + ks * 32 + g * 8);
#pragma unroll
        for (int dc = 0; dc < 8; ++dc) {
          int d = dc * 16 + r_lo;
          bf16x8 Vb8 = *(const bf16x8*)(Vg + (long)d * 2048 + ks * 32 + g * 8);
          Oa[dc] = mfma16(Pa, Vb8, Oa[dc]);
        }
      }
      __builtin_amdgcn_s_setprio(0);
    }
    __builtin_amdgcn_s_barrier();
  }

  // ---- epilogue: normalize and store fp32 ----
#pragma unroll
  for (int r = 0; r < 4; ++r) {
    float li = 1.f / __shfl(lrun, g * 4 + r);
    long orow = b * 2048 + qt * 64 + w * 16 + g * 4 + r;
#pragma unroll
    for (int dc = 0; dc < 8; ++dc) {
      out[orow * 128 + dc * 16 + r_lo] = Oa[dc][r] * li;
    }
  }
}

extern "C" void kernel_launch(void* const* d_in, const int* in_sizes, int n_in,
                              void* d_out, int out_size, void* d_ws, size_t ws_size,
                              hipStream_t stream) {
  const float* x     = (const float*)d_in[0];
  const float* wqk_w = (const float*)d_in[1];
  const float* wqk_b = (const float*)d_in[2];
  const float* wv_w  = (const float*)d_in[3];
  const float* wv_b  = (const float*)d_in[4];
  float* out = (float*)d_out;

  unsigned short* qk_h  = (unsigned short*)d_ws;             // 32768*128
  unsigned short* vT    = qk_h + 32768 * 128;                // [16][128][2048]
  unsigned short* Wqk_h = vT + 16 * 128 * 2048;              // [128][1024]
  unsigned short* Wv_h  = Wqk_h + 128 * 1024;

  hipLaunchKernelGGL(kprep, dim3(512), dim3(256), 0, stream,
                     wqk_w, wv_w, Wqk_h, Wv_h);
  hipLaunchKernelGGL(kproj, dim3(512), dim3(256), 2 * PBUF_B, stream,
                     x, Wqk_h, Wv_h, wqk_b, wv_b, qk_h, vT);
  hipLaunchKernelGGL(kattn, dim3(512), dim3(256), 0, stream,
                     qk_h, vT, out);
}